// Round 2
// baseline (14161.038 us; speedup 1.0000x reference)
//
#include <hip/hip_runtime.h>
#include <hip/hip_bf16.h>

// ---------------------------------------------------------------------------
// AJ-RNN forward: 2-layer LSTM (B=128,T=256,D=64,H=512) with missing-value
// imputation. Round 5: single PERSISTENT kernel (round-4 design, fence fixed).
//  - weights register-resident (66 bf16x8 fragments = 264 VGPR/lane, loaded once)
//  - c1/c2 cell state in registers (fixed thread->element map across time)
//  - h1/h2 exchanged through LLC with per-rg-group (32-block) spin barriers
//    (monotonic counter; all-thread __threadfence() release/acquire pattern)
//  - h tiles staged global->LDS via global_load_lds(16B) with XOR-swizzled
//    source so ds_read_b128 A-fragments are bank-conflict-free
//  - 1 block/CU forced via >80KB LDS => all 256 blocks co-resident (capacity
//    argument), spin barriers deadlock-free without cooperative launch
// ---------------------------------------------------------------------------

typedef __bf16  v8bf  __attribute__((ext_vector_type(8)));
typedef float   f32x4 __attribute__((ext_vector_type(4)));

constexpr int B_ = 128, T_ = 256, D_ = 64, H_ = 512;

// workspace layout (bytes)
constexpr size_t OFF_WP1 = 0;        // packed [k0;r0] bf16 -> 2359296 B
constexpr size_t OFF_WP2 = 2359296;  // packed [k1;r1] bf16 -> 4194304 B
constexpr size_t OFF_WPP = 6553600;  // packed W bf16       ->   65536 B
constexpr size_t OFF_H1A = 6619136;  // h1 ping bf16           131072 B
constexpr size_t OFF_H1B = 6750208;  // h1 pong bf16           131072 B
constexpr size_t OFF_H2A = 6881280;  // h2 ping bf16           131072 B
constexpr size_t OFF_H2B = 7012352;  // h2 pong bf16           131072 B
constexpr size_t OFF_FLG = 7143424;  // 8 groups * 64 u32 =      2048 B
// total 7145472 B

__device__ __forceinline__ v8bf ldv(const __hip_bfloat16* p) {
  return *reinterpret_cast<const v8bf*>(p);
}
__device__ __forceinline__ float sigf(float x) { return 1.0f / (1.0f + __expf(-x)); }
__device__ __forceinline__ float tanhfast(float x) {
  x = fminf(15.0f, fmaxf(-15.0f, x));
  float e = __expf(-2.0f * x);
  return (1.0f - e) / (1.0f + e);
}

// async global->LDS, 16 bytes per lane. LDS dest: wave-uniform base + lane*16.
__device__ __forceinline__ void g2l16(const void* g, void* l) {
  __builtin_amdgcn_global_load_lds(
      (const __attribute__((address_space(1))) void*)g,
      (__attribute__((address_space(3))) void*)l, 16, 0, 0);
}

// ---------------------------------------------------------------------------
// Pack B-operand fragments (float32 in, bf16 out):
// out[((ct*nkc + kc)*64 + lane)*8 + j] = Wcat[kc*32 + (lane>>4)*8 + j][ct*16 + (lane&15)]
// ---------------------------------------------------------------------------
__global__ __launch_bounds__(256) void pack_weights(
    const float* __restrict__ kp, const float* __restrict__ rp,
    int krows, int ncols, int nkc, int nct, __hip_bfloat16* __restrict__ out) {
  int tid = blockIdx.x * 256 + threadIdx.x;
  int total = nct * nkc * 64;
  if (tid >= total) return;
  int L  = tid & 63;
  int kc = (tid >> 6) % nkc;
  int ct = tid / (64 * nkc);
  int n  = ct * 16 + (L & 15);
  int kb = kc * 32 + (L >> 4) * 8;
  __hip_bfloat16* dst = out + (size_t)tid * 8;
#pragma unroll
  for (int j = 0; j < 8; ++j) {
    int kk = kb + j;
    float v = (kk < krows) ? kp[kk * ncols + n] : rp[(kk - krows) * ncols + n];
    dst[j] = __float2bfloat16(v);
  }
}

// zero h1 ping, h2 ping, barrier counters (ws re-poisoned before every call)
__global__ __launch_bounds__(256) void init_state(
    __hip_bfloat16* __restrict__ h1a, __hip_bfloat16* __restrict__ h2a,
    unsigned* __restrict__ flg) {
  int idx = blockIdx.x * 256 + threadIdx.x;   // 65536 total
  h1a[idx] = __float2bfloat16(0.0f);
  h2a[idx] = __float2bfloat16(0.0f);
  if (idx < 512) flg[idx] = 0u;
}

// ---------------------------------------------------------------------------
// Persistent recurrence kernel. Block = (rg,cg): 16 batch rows x 16 h-cols,
// 4 waves (one z-gate column-tile each). 8 independent rg-chains of 32 blocks.
// ---------------------------------------------------------------------------
__global__ __launch_bounds__(256, 1) void rnn_persist(
    const float* __restrict__ x,
    const __hip_bfloat16* __restrict__ Wp1,
    const __hip_bfloat16* __restrict__ Wp2,
    const __hip_bfloat16* __restrict__ WpP,
    const float* __restrict__ b0,
    const float* __restrict__ b1,
    const float* __restrict__ biasD,
    __hip_bfloat16* __restrict__ h1a, __hip_bfloat16* __restrict__ h1b,
    __hip_bfloat16* __restrict__ h2a, __hip_bfloat16* __restrict__ h2b,
    unsigned* __restrict__ flg,
    float* __restrict__ pred_out,
    float* __restrict__ last_out) {

  // h tiles: 1024 B rows, XOR-swizzled storage (phys_byte = log_byte ^ ((row&7)<<4))
  __shared__ alignas(16) __hip_bfloat16 h1L[16][512];  // h1_{t-1}
  __shared__ alignas(16) __hip_bfloat16 h2L[16][512];  // h2_{t-1}
  __shared__ alignas(16) __hip_bfloat16 h1N[16][512];  // h1_t
  __shared__ alignas(16) __hip_bfloat16 curL[16][72];
  __shared__ alignas(16) float predb[16][68];
  __shared__ float zb[4][16][17];
  __shared__ char ldspad[24576];   // push static LDS > 80KB => 1 block/CU

  const int rg = blockIdx.x >> 5;
  const int cg = blockIdx.x & 31;
  const int w  = threadIdx.x >> 6;
  const int L  = threadIdx.x & 63;
  const int m  = L & 15;
  const int q  = L >> 4;
  const int row2 = threadIdx.x >> 4;
  const int col2 = threadIdx.x & 15;
  const int C  = cg * 16 + col2;
  const int R  = rg * 16 + row2;
  const int sw = (m & 7) << 3;     // element-unit LDS read swizzle for row m

  // keep ldspad allocated (condition is never true for aligned ws; body harmless)
  if (((size_t)flg & 0xfffu) == 0xabcu) ldspad[threadIdx.x] = 1;

  // ---- load all weight fragments into registers (once) ----
  v8bf wpp[16], wp1[18], wp2[32];
  {
    const int ct = w * 32 + cg;
#pragma unroll
    for (int kc = 0; kc < 16; ++kc)
      wpp[kc] = ldv(WpP + ((size_t)(w * 16 + kc) * 64 + L) * 8);
#pragma unroll
    for (int kc = 0; kc < 18; ++kc)
      wp1[kc] = ldv(Wp1 + ((size_t)(ct * 18 + kc) * 64 + L) * 8);
#pragma unroll
    for (int kc = 0; kc < 32; ++kc)
      wp2[kc] = ldv(Wp2 + ((size_t)(ct * 32 + kc) * 64 + L) * 8);
  }
  const float b0i = b0[C], b0f = b0[512 + C], b0g = b0[1024 + C], b0o = b0[1536 + C];
  const float b1i = b1[C], b1f = b1[512 + C], b1g = b1[1024 + C], b1o = b1[1536 + C];
  const float bD  = biasD[w * 16 + m];

  float c1v = 0.0f, c2v = 0.0f;   // cell state lives in registers

  const size_t rgbase = (size_t)rg * 16 * H_;          // element offset of row tile
  const float* xrow = x + (size_t)R * T_ * D_;
  float* prow = pred_out + (size_t)R * (T_ - 1) * D_;
  unsigned* cnt = flg + rg * 64;                       // per-rg barrier counter
  const int hidx = R * H_ + C;

  for (int t = 0; t < T_; ++t) {
    const __hip_bfloat16* h1r = (t & 1) ? h1b : h1a;
    __hip_bfloat16*       h1w = (t & 1) ? h1a : h1b;
    const __hip_bfloat16* h2r = (t & 1) ? h2b : h2a;
    __hip_bfloat16*       h2w = (t & 1) ? h2a : h2b;

    // ---- stage h1_{t-1} -> h1L, h2_{t-1} -> h2L (pre-swizzled source) ----
    {
      const char* g1 = (const char*)(h1r + rgbase);
      const char* g2 = (const char*)(h2r + rgbase);
#pragma unroll
      for (int i = 0; i < 4; ++i) {
        const int row  = i * 4 + w;                    // 1KB chunk == one row
        const int goff = row * 1024 + ((L * 16) ^ ((row & 7) << 4));
        g2l16(g1 + goff, &h1L[row][0]);
        g2l16(g2 + goff, &h2L[row][0]);
      }
    }
    __syncthreads();   // drains vmcnt -> LDS tiles ready

    // ---- Phase A: pred = h2_{t-1} @ W + bias (wave w: cols w*16..w*16+15) ----
    if (t > 0) {
      f32x4 a0 = {0.f,0.f,0.f,0.f}, a1 = {0.f,0.f,0.f,0.f};
#pragma unroll
      for (int kc = 0; kc < 16; kc += 2) {
        v8bf x0 = ldv(&h2L[m][(kc * 32 + q * 8) ^ sw]);
        v8bf x1 = ldv(&h2L[m][((kc + 1) * 32 + q * 8) ^ sw]);
        a0 = __builtin_amdgcn_mfma_f32_16x16x32_bf16(x0, wpp[kc],     a0, 0, 0, 0);
        a1 = __builtin_amdgcn_mfma_f32_16x16x32_bf16(x1, wpp[kc + 1], a1, 0, 0, 0);
      }
      a0 += a1;
#pragma unroll
      for (int r = 0; r < 4; ++r) predb[q * 4 + r][w * 16 + m] = a0[r] + bD;
    }
    __syncthreads();

    // ---- Phase 2: cur build (bf16 in LDS); cg==0 streams pred -> d_out ----
    {
      const int c0 = col2 * 4;
      const float4 xv = *reinterpret_cast<const float4*>(xrow + t * D_ + c0);
      const float4 pv = *reinterpret_cast<const float4*>(&predb[row2][c0]); // t=0: unused garbage
      const float xa[4] = {xv.x, xv.y, xv.z, xv.w};
      const float pa[4] = {pv.x, pv.y, pv.z, pv.w};
#pragma unroll
      for (int j = 0; j < 4; ++j) {
        const bool missv = (t > 0) && (xa[j] == 128.0f);
        curL[row2][c0 + j] = __float2bfloat16(missv ? pa[j] : xa[j]);
      }
      if (cg == 0 && t > 0)
        *reinterpret_cast<float4*>(prow + (size_t)(t - 1) * D_ + c0) = pv;
    }
    __syncthreads();

    // ---- Phase 3: z1 tile for gate w, K = 64 (cur) + 512 (h1_{t-1}) ----
    {
      f32x4 z0 = {0.f,0.f,0.f,0.f}, z1v = {0.f,0.f,0.f,0.f};
      {
        v8bf xa0 = ldv(&curL[m][q * 8]);
        v8bf xa1 = ldv(&curL[m][32 + q * 8]);
        z0  = __builtin_amdgcn_mfma_f32_16x16x32_bf16(xa0, wp1[0], z0, 0, 0, 0);
        z1v = __builtin_amdgcn_mfma_f32_16x16x32_bf16(xa1, wp1[1], z1v, 0, 0, 0);
      }
#pragma unroll
      for (int kc = 2; kc < 18; kc += 2) {
        v8bf xa0 = ldv(&h1L[m][((kc - 2) * 32 + q * 8) ^ sw]);
        v8bf xa1 = ldv(&h1L[m][((kc - 1) * 32 + q * 8) ^ sw]);
        z0  = __builtin_amdgcn_mfma_f32_16x16x32_bf16(xa0, wp1[kc],     z0, 0, 0, 0);
        z1v = __builtin_amdgcn_mfma_f32_16x16x32_bf16(xa1, wp1[kc + 1], z1v, 0, 0, 0);
      }
      z0 += z1v;
#pragma unroll
      for (int r = 0; r < 4; ++r) zb[w][q * 4 + r][m] = z0[r];
    }
    __syncthreads();

    // ---- Phase 4: L1 gates + h1_t store ----
    {
      float iv = zb[0][row2][col2] + b0i;
      float fv = zb[1][row2][col2] + b0f;
      float gv = zb[2][row2][col2] + b0g;
      float ov = zb[3][row2][col2] + b0o;
      float ig = sigf(iv), fg = sigf(fv), gg = tanhfast(gv), og = sigf(ov);
      c1v = fg * c1v + ig * gg;
      float hn = og * tanhfast(c1v);
      h1w[hidx] = __float2bfloat16(hn);
    }

    // ---- group barrier 1 (h1_t visible to all 32 blocks of this rg) ----
    __syncthreads();        // all h1 stores issued block-wide
    __threadfence();        // each thread's stores -> device scope
    __syncthreads();        // fences complete before the signal
    if (threadIdx.x == 0)
      __hip_atomic_fetch_add(cnt, 1u, __ATOMIC_RELAXED, __HIP_MEMORY_SCOPE_AGENT);
    {
      const unsigned tgt = 32u * (2u * (unsigned)t + 1u);
      if (threadIdx.x < 64) {
        while (__hip_atomic_load(cnt, __ATOMIC_RELAXED, __HIP_MEMORY_SCOPE_AGENT) < tgt)
          __builtin_amdgcn_s_sleep(1);
        __threadfence();    // acquire: discard stale cached h lines
      }
      __syncthreads();
    }

    // ---- stage h1_t -> h1N ----
    {
      const char* g1 = (const char*)(h1w + rgbase);
#pragma unroll
      for (int i = 0; i < 4; ++i) {
        const int row  = i * 4 + w;
        const int goff = row * 1024 + ((L * 16) ^ ((row & 7) << 4));
        g2l16(g1 + goff, &h1N[row][0]);
      }
    }
    __syncthreads();

    // ---- Phase 5: z2 tile for gate w, K = 512 (h1_t) + 512 (h2_{t-1}) ----
    {
      f32x4 z0 = {0.f,0.f,0.f,0.f}, z1v = {0.f,0.f,0.f,0.f};
      f32x4 z2v = {0.f,0.f,0.f,0.f}, z3v = {0.f,0.f,0.f,0.f};
#pragma unroll
      for (int kc = 0; kc < 16; kc += 4) {
        v8bf x0 = ldv(&h1N[m][(kc * 32 + q * 8) ^ sw]);
        v8bf x1 = ldv(&h1N[m][((kc + 1) * 32 + q * 8) ^ sw]);
        v8bf x2 = ldv(&h1N[m][((kc + 2) * 32 + q * 8) ^ sw]);
        v8bf x3 = ldv(&h1N[m][((kc + 3) * 32 + q * 8) ^ sw]);
        z0  = __builtin_amdgcn_mfma_f32_16x16x32_bf16(x0, wp2[kc],     z0, 0, 0, 0);
        z1v = __builtin_amdgcn_mfma_f32_16x16x32_bf16(x1, wp2[kc + 1], z1v, 0, 0, 0);
        z2v = __builtin_amdgcn_mfma_f32_16x16x32_bf16(x2, wp2[kc + 2], z2v, 0, 0, 0);
        z3v = __builtin_amdgcn_mfma_f32_16x16x32_bf16(x3, wp2[kc + 3], z3v, 0, 0, 0);
      }
#pragma unroll
      for (int kc = 16; kc < 32; kc += 4) {
        v8bf x0 = ldv(&h2L[m][((kc - 16) * 32 + q * 8) ^ sw]);
        v8bf x1 = ldv(&h2L[m][((kc - 15) * 32 + q * 8) ^ sw]);
        v8bf x2 = ldv(&h2L[m][((kc - 14) * 32 + q * 8) ^ sw]);
        v8bf x3 = ldv(&h2L[m][((kc - 13) * 32 + q * 8) ^ sw]);
        z0  = __builtin_amdgcn_mfma_f32_16x16x32_bf16(x0, wp2[kc],     z0, 0, 0, 0);
        z1v = __builtin_amdgcn_mfma_f32_16x16x32_bf16(x1, wp2[kc + 1], z1v, 0, 0, 0);
        z2v = __builtin_amdgcn_mfma_f32_16x16x32_bf16(x2, wp2[kc + 2], z2v, 0, 0, 0);
        z3v = __builtin_amdgcn_mfma_f32_16x16x32_bf16(x3, wp2[kc + 3], z3v, 0, 0, 0);
      }
      z0 = (z0 + z1v) + (z2v + z3v);
#pragma unroll
      for (int r = 0; r < 4; ++r) zb[w][q * 4 + r][m] = z0[r];
    }
    __syncthreads();

    // ---- Phase 6: L2 gates + h2_t store (+ last_cell at t==T-1) ----
    {
      float iv = zb[0][row2][col2] + b1i;
      float fv = zb[1][row2][col2] + b1f;
      float gv = zb[2][row2][col2] + b1g;
      float ov = zb[3][row2][col2] + b1o;
      float ig = sigf(iv), fg = sigf(fv), gg = tanhfast(gv), og = sigf(ov);
      c2v = fg * c2v + ig * gg;
      float hn = og * tanhfast(c2v);
      h2w[hidx] = __float2bfloat16(hn);
      if (t == T_ - 1) last_out[hidx] = hn;
    }
    if (t == T_ - 1) break;   // outputs complete; skip final barrier

    // ---- group barrier 2 (h2_t visible before next step's pred/z2) ----
    __syncthreads();
    __threadfence();
    __syncthreads();
    if (threadIdx.x == 0)
      __hip_atomic_fetch_add(cnt, 1u, __ATOMIC_RELAXED, __HIP_MEMORY_SCOPE_AGENT);
    {
      const unsigned tgt = 32u * (2u * (unsigned)t + 2u);
      if (threadIdx.x < 64) {
        while (__hip_atomic_load(cnt, __ATOMIC_RELAXED, __HIP_MEMORY_SCOPE_AGENT) < tgt)
          __builtin_amdgcn_s_sleep(1);
        __threadfence();
      }
      __syncthreads();
    }
  }
}

// ---------------------------------------------------------------------------
extern "C" void kernel_launch(void* const* d_in, const int* in_sizes, int n_in,
                              void* d_out, int out_size, void* d_ws, size_t ws_size,
                              hipStream_t stream) {
  const float* x    = (const float*)d_in[0];
  const float* k0   = (const float*)d_in[1];
  const float* r0   = (const float*)d_in[2];
  const float* b0   = (const float*)d_in[3];
  const float* k1   = (const float*)d_in[4];
  const float* r1   = (const float*)d_in[5];
  const float* b1   = (const float*)d_in[6];
  const float* W    = (const float*)d_in[7];
  const float* bias = (const float*)d_in[8];

  char* ws = (char*)d_ws;
  __hip_bfloat16* Wp1 = (__hip_bfloat16*)(ws + OFF_WP1);
  __hip_bfloat16* Wp2 = (__hip_bfloat16*)(ws + OFF_WP2);
  __hip_bfloat16* WpP = (__hip_bfloat16*)(ws + OFF_WPP);
  __hip_bfloat16* h1a = (__hip_bfloat16*)(ws + OFF_H1A);
  __hip_bfloat16* h1b = (__hip_bfloat16*)(ws + OFF_H1B);
  __hip_bfloat16* h2a = (__hip_bfloat16*)(ws + OFF_H2A);
  __hip_bfloat16* h2b = (__hip_bfloat16*)(ws + OFF_H2B);
  unsigned*       flg = (unsigned*)(ws + OFF_FLG);

  pack_weights<<<(128 * 18 * 64 + 255) / 256, 256, 0, stream>>>(k0, r0, 64, 2048, 18, 128, Wp1);
  pack_weights<<<(128 * 32 * 64 + 255) / 256, 256, 0, stream>>>(k1, r1, 512, 2048, 32, 128, Wp2);
  pack_weights<<<(4 * 16 * 64 + 255) / 256, 256, 0, stream>>>(W, W, 512, 64, 16, 4, WpP);
  init_state<<<256, 256, 0, stream>>>(h1a, h2a, flg);

  float* outp = (float*)d_out;
  float* last = outp + (size_t)B_ * (T_ - 1) * D_;

  rnn_persist<<<256, 256, 0, stream>>>(x, Wp1, Wp2, WpP, b0, b1, bias,
                                       h1a, h1b, h2a, h2b, flg, outp, last);
}

// Round 3
// 1550.581 us; speedup vs baseline: 9.1327x; 9.1327x over previous
//
#include <hip/hip_runtime.h>
#include <hip/hip_bf16.h>

// ---------------------------------------------------------------------------
// AJ-RNN forward: 2-layer LSTM (B=128,T=256,D=64,H=512) with missing-value
// imputation. Round 6: persistent kernel, FENCE-FREE h-exchange.
//  - R5 post-mortem: __threadfence() by all threads 2x/step = L2 wbl2/inv
//    storm -> 55us/step idle (MfmaUtil 0.8%). Fix: h stores/loads go to the
//    LLC coherence point directly (sc0 sc1), so NO cache maintenance needed.
//  - weights register-resident (66 bf16x8 fragments/lane, loaded once)
//  - cell state c1/c2 in registers; h1(t-1) carried in LDS ping-pong (staged
//    once as h1N, reused next step as h1L - no global re-read)
//  - barrier = vmcnt drain + relaxed agent fetch_add + relaxed agent poll
//  - barrier-1 latency overlapped with z2's h2(t-1) half (16 MFMAs)
// ---------------------------------------------------------------------------

typedef __bf16        v8bf  __attribute__((ext_vector_type(8)));
typedef float         f32x4 __attribute__((ext_vector_type(4)));
typedef unsigned int  u32x4 __attribute__((ext_vector_type(4)));

constexpr int B_ = 128, T_ = 256, D_ = 64, H_ = 512;

// workspace layout (bytes)
constexpr size_t OFF_WP1 = 0;        // packed [k0;r0] bf16 -> 2359296 B
constexpr size_t OFF_WP2 = 2359296;  // packed [k1;r1] bf16 -> 4194304 B
constexpr size_t OFF_WPP = 6553600;  // packed W bf16       ->   65536 B
constexpr size_t OFF_H1G = 6619136;  // h1 exchange bf16       131072 B
constexpr size_t OFF_H2G = 6750208;  // h2 exchange bf16       131072 B
constexpr size_t OFF_FLG = 6881280;  // 8 groups * 64 u32 =      2048 B

__device__ __forceinline__ v8bf ldv(const __hip_bfloat16* p) {
  return *reinterpret_cast<const v8bf*>(p);
}
__device__ __forceinline__ float sigf(float x) { return 1.0f / (1.0f + __expf(-x)); }
__device__ __forceinline__ float tanhfast(float x) {
  x = fminf(15.0f, fmaxf(-15.0f, x));
  float e = __expf(-2.0f * x);
  return (1.0f - e) / (1.0f + e);
}

// 16-bit store straight to the device coherence point (LLC): agent-visible
// without any L2 writeback.
__device__ __forceinline__ void st_llc_u16(void* p, unsigned v) {
  asm volatile("global_store_short %0, %1, off sc0 sc1" :: "v"(p), "v"(v) : "memory");
}

// 64B load from the coherence point (bypass L1/L2 -> never stale), 4 loads
// in flight, one waitcnt.
__device__ __forceinline__ void ld_llc64(const char* g, u32x4& a, u32x4& b,
                                         u32x4& c, u32x4& d) {
  asm volatile(
      "global_load_dwordx4 %0, %4, off sc0 sc1\n\t"
      "global_load_dwordx4 %1, %4, off offset:16 sc0 sc1\n\t"
      "global_load_dwordx4 %2, %4, off offset:32 sc0 sc1\n\t"
      "global_load_dwordx4 %3, %4, off offset:48 sc0 sc1\n\t"
      "s_waitcnt vmcnt(0)"
      : "=&v"(a), "=&v"(b), "=&v"(c), "=&v"(d)
      : "v"(g)
      : "memory");
}

// stage 16x512 bf16 tile (linear global, agent-visible) -> XOR-swizzled LDS
// (phys_byte_in_row = log_byte ^ ((row&7)<<4)); b128 writes are conflict-free.
__device__ __forceinline__ void stage_tile(const __hip_bfloat16* gsrc,
                                           __hip_bfloat16 (*tile)[512], int tid) {
  const int row = tid >> 4;
  const int o0  = (tid & 15) * 64;
  const char* g = (const char*)gsrc + row * 1024 + o0;
  char* lb = (char*)(&tile[row][0]);
  const int sw = (row & 7) << 4;
  u32x4 a, b, c, d;
  ld_llc64(g, a, b, c, d);
  *(u32x4*)(lb + ((o0 +  0) ^ sw)) = a;
  *(u32x4*)(lb + ((o0 + 16) ^ sw)) = b;
  *(u32x4*)(lb + ((o0 + 32) ^ sw)) = c;
  *(u32x4*)(lb + ((o0 + 48) ^ sw)) = d;
}

// ---------------------------------------------------------------------------
// Pack B-operand fragments (float32 in, bf16 out):
// out[((ct*nkc + kc)*64 + lane)*8 + j] = Wcat[kc*32 + (lane>>4)*8 + j][ct*16 + (lane&15)]
// ---------------------------------------------------------------------------
__global__ __launch_bounds__(256) void pack_weights(
    const float* __restrict__ kp, const float* __restrict__ rp,
    int krows, int ncols, int nkc, int nct, __hip_bfloat16* __restrict__ out) {
  int tid = blockIdx.x * 256 + threadIdx.x;
  int total = nct * nkc * 64;
  if (tid >= total) return;
  int L  = tid & 63;
  int kc = (tid >> 6) % nkc;
  int ct = tid / (64 * nkc);
  int n  = ct * 16 + (L & 15);
  int kb = kc * 32 + (L >> 4) * 8;
  __hip_bfloat16* dst = out + (size_t)tid * 8;
#pragma unroll
  for (int j = 0; j < 8; ++j) {
    int kk = kb + j;
    float v = (kk < krows) ? kp[kk * ncols + n] : rp[(kk - krows) * ncols + n];
    dst[j] = __float2bfloat16(v);
  }
}

// zero h1/h2 exchange buffers + barrier counters (ws re-poisoned every call)
__global__ __launch_bounds__(256) void init_state(
    __hip_bfloat16* __restrict__ h1g, __hip_bfloat16* __restrict__ h2g,
    unsigned* __restrict__ flg) {
  int idx = blockIdx.x * 256 + threadIdx.x;   // 65536 total
  h1g[idx] = __float2bfloat16(0.0f);
  h2g[idx] = __float2bfloat16(0.0f);
  if (idx < 512) flg[idx] = 0u;
}

// ---------------------------------------------------------------------------
// Persistent recurrence kernel. Block = (rg,cg): 16 batch rows x 16 h-cols,
// 4 waves (one z-gate column-tile each). 8 independent rg-chains of 32 blocks.
// rg = blockIdx&7 so a chain's blocks likely share an XCD (perf only).
// ---------------------------------------------------------------------------
__global__ __launch_bounds__(256, 1) void rnn_persist(
    const float* __restrict__ x,
    const __hip_bfloat16* __restrict__ Wp1,
    const __hip_bfloat16* __restrict__ Wp2,
    const __hip_bfloat16* __restrict__ WpP,
    const float* __restrict__ b0,
    const float* __restrict__ b1,
    const float* __restrict__ biasD,
    __hip_bfloat16* __restrict__ h1g,
    __hip_bfloat16* __restrict__ h2g,
    unsigned* __restrict__ flg,
    float* __restrict__ pred_out,
    float* __restrict__ last_out) {

  __shared__ alignas(16) __hip_bfloat16 h1P[16][512];  // h1 LDS ping
  __shared__ alignas(16) __hip_bfloat16 h1Q[16][512];  // h1 LDS pong
  __shared__ alignas(16) __hip_bfloat16 h2L[16][512];  // h2_{t-1}
  __shared__ alignas(16) __hip_bfloat16 curL[16][72];
  __shared__ alignas(16) float predb[16][68];
  __shared__ float zb[4][16][17];

  const int tid = threadIdx.x;
  const int rg = blockIdx.x & 7;     // likely-XCD-local group
  const int cg = blockIdx.x >> 3;
  const int w  = tid >> 6;
  const int L  = tid & 63;
  const int m  = L & 15;
  const int q  = L >> 4;
  const int row2 = tid >> 4;
  const int col2 = tid & 15;
  const int C  = cg * 16 + col2;
  const int R  = rg * 16 + row2;
  const int sw = (m & 7) << 3;       // element-unit LDS read swizzle for row m

  // ---- load all weight fragments into registers (once) ----
  v8bf wpp[16], wp1[18], wp2[32];
  {
    const int ct = w * 32 + cg;
#pragma unroll
    for (int kc = 0; kc < 16; ++kc)
      wpp[kc] = ldv(WpP + ((size_t)(w * 16 + kc) * 64 + L) * 8);
#pragma unroll
    for (int kc = 0; kc < 18; ++kc)
      wp1[kc] = ldv(Wp1 + ((size_t)(ct * 18 + kc) * 64 + L) * 8);
#pragma unroll
    for (int kc = 0; kc < 32; ++kc)
      wp2[kc] = ldv(Wp2 + ((size_t)(ct * 32 + kc) * 64 + L) * 8);
  }
  const float b0i = b0[C], b0f = b0[512 + C], b0g = b0[1024 + C], b0o = b0[1536 + C];
  const float b1i = b1[C], b1f = b1[512 + C], b1g = b1[1024 + C], b1o = b1[1536 + C];
  const float bD  = biasD[w * 16 + m];

  float c1v = 0.0f, c2v = 0.0f;      // cell state lives in registers

  const size_t rgbase = (size_t)rg * 16 * H_;
  const float* xrow = x + (size_t)R * T_ * D_;
  float* prow = pred_out + (size_t)R * (T_ - 1) * D_;
  unsigned* cnt = flg + rg * 64;
  const int hidx = R * H_ + C;

  // prologue: h1(-1)=0 staged into ping buffer
  stage_tile(h1g + rgbase, h1P, tid);

  for (int t = 0; t < T_; ++t) {
    __hip_bfloat16 (*h1L)[512] = (t & 1) ? h1Q : h1P;  // h1_{t-1}
    __hip_bfloat16 (*h1N)[512] = (t & 1) ? h1P : h1Q;  // h1_t (staged below)

    // x prefetch for this step (input, no barrier dependency)
    const int c0 = col2 * 4;
    const float4 xv = *reinterpret_cast<const float4*>(xrow + t * D_ + c0);

    // ---- wait barrier-2(t-1): h2(t-1) visible at LLC ----
    if (t > 0) {
      const unsigned tgt = 64u * (unsigned)t;          // 32*(2(t-1)+2)
      if (tid < 64) {
        while (__hip_atomic_load(cnt, __ATOMIC_RELAXED, __HIP_MEMORY_SCOPE_AGENT) < tgt)
          __builtin_amdgcn_s_sleep(1);
      }
    }
    __syncthreads();

    // ---- stage h2(t-1) -> h2L (LLC loads, swizzled LDS) ----
    stage_tile(h2g + rgbase, h2L, tid);
    __syncthreads();

    // ---- Phase A: pred = h2_{t-1} @ W + bias ----
    if (t > 0) {
      f32x4 a0 = {0.f,0.f,0.f,0.f}, a1 = {0.f,0.f,0.f,0.f};
#pragma unroll
      for (int kc = 0; kc < 16; kc += 2) {
        v8bf x0 = ldv(&h2L[m][(kc * 32 + q * 8) ^ sw]);
        v8bf x1 = ldv(&h2L[m][((kc + 1) * 32 + q * 8) ^ sw]);
        a0 = __builtin_amdgcn_mfma_f32_16x16x32_bf16(x0, wpp[kc],     a0, 0, 0, 0);
        a1 = __builtin_amdgcn_mfma_f32_16x16x32_bf16(x1, wpp[kc + 1], a1, 0, 0, 0);
      }
      a0 += a1;
#pragma unroll
      for (int r = 0; r < 4; ++r) predb[q * 4 + r][w * 16 + m] = a0[r] + bD;
    }
    __syncthreads();

    // ---- Phase 2: cur build (bf16 in LDS); cg==0 streams pred -> d_out ----
    {
      const float4 pv = *reinterpret_cast<const float4*>(&predb[row2][c0]); // t=0: unused
      const float xa[4] = {xv.x, xv.y, xv.z, xv.w};
      const float pa[4] = {pv.x, pv.y, pv.z, pv.w};
#pragma unroll
      for (int j = 0; j < 4; ++j) {
        const bool missv = (t > 0) && (xa[j] == 128.0f);
        curL[row2][c0 + j] = __float2bfloat16(missv ? pa[j] : xa[j]);
      }
      if (cg == 0 && t > 0)
        *reinterpret_cast<float4*>(prow + (size_t)(t - 1) * D_ + c0) = pv;
    }
    __syncthreads();

    // ---- Phase 3: z1 tile for gate w, K = 64 (cur) + 512 (h1_{t-1}) ----
    {
      f32x4 z0 = {0.f,0.f,0.f,0.f}, z1v = {0.f,0.f,0.f,0.f};
      {
        v8bf xa0 = ldv(&curL[m][q * 8]);
        v8bf xa1 = ldv(&curL[m][32 + q * 8]);
        z0  = __builtin_amdgcn_mfma_f32_16x16x32_bf16(xa0, wp1[0], z0, 0, 0, 0);
        z1v = __builtin_amdgcn_mfma_f32_16x16x32_bf16(xa1, wp1[1], z1v, 0, 0, 0);
      }
#pragma unroll
      for (int kc = 2; kc < 18; kc += 2) {
        v8bf xa0 = ldv(&h1L[m][((kc - 2) * 32 + q * 8) ^ sw]);
        v8bf xa1 = ldv(&h1L[m][((kc - 1) * 32 + q * 8) ^ sw]);
        z0  = __builtin_amdgcn_mfma_f32_16x16x32_bf16(xa0, wp1[kc],     z0, 0, 0, 0);
        z1v = __builtin_amdgcn_mfma_f32_16x16x32_bf16(xa1, wp1[kc + 1], z1v, 0, 0, 0);
      }
      z0 += z1v;
#pragma unroll
      for (int r = 0; r < 4; ++r) zb[w][q * 4 + r][m] = z0[r];
    }
    __syncthreads();

    // ---- Phase 4: L1 gates + h1_t store (straight to LLC) ----
    {
      float iv = zb[0][row2][col2] + b0i;
      float fv = zb[1][row2][col2] + b0f;
      float gv = zb[2][row2][col2] + b0g;
      float ov = zb[3][row2][col2] + b0o;
      float ig = sigf(iv), fg = sigf(fv), gg = tanhfast(gv), og = sigf(ov);
      c1v = fg * c1v + ig * gg;
      float hn = og * tanhfast(c1v);
      st_llc_u16(&h1g[hidx], (unsigned)__builtin_bit_cast(unsigned short,
                                                          __float2bfloat16(hn)));
    }

    // ---- signal barrier-1 (no cache maintenance: stores already at LLC) ----
    asm volatile("s_waitcnt vmcnt(0)" ::: "memory");
    __syncthreads();
    if (tid == 0)
      __hip_atomic_fetch_add(cnt, 1u, __ATOMIC_RELAXED, __HIP_MEMORY_SCOPE_AGENT);

    // ---- Phase 5a (overlaps barrier-1): z2 h2(t-1) half ----
    f32x4 zB0 = {0.f,0.f,0.f,0.f}, zB1 = {0.f,0.f,0.f,0.f};
#pragma unroll
    for (int kc = 0; kc < 16; kc += 2) {
      v8bf x0 = ldv(&h2L[m][(kc * 32 + q * 8) ^ sw]);
      v8bf x1 = ldv(&h2L[m][((kc + 1) * 32 + q * 8) ^ sw]);
      zB0 = __builtin_amdgcn_mfma_f32_16x16x32_bf16(x0, wp2[16 + kc],     zB0, 0, 0, 0);
      zB1 = __builtin_amdgcn_mfma_f32_16x16x32_bf16(x1, wp2[16 + kc + 1], zB1, 0, 0, 0);
    }

    // ---- wait barrier-1: h1_t visible; stage h1_t -> h1N ----
    {
      const unsigned tgt = 32u * (2u * (unsigned)t + 1u);
      if (tid < 64) {
        while (__hip_atomic_load(cnt, __ATOMIC_RELAXED, __HIP_MEMORY_SCOPE_AGENT) < tgt)
          __builtin_amdgcn_s_sleep(1);
      }
    }
    __syncthreads();
    stage_tile(h1g + rgbase, h1N, tid);
    __syncthreads();

    // ---- Phase 5b: z2 h1_t half; combine ----
    {
      f32x4 zA0 = {0.f,0.f,0.f,0.f}, zA1 = {0.f,0.f,0.f,0.f};
#pragma unroll
      for (int kc = 0; kc < 16; kc += 2) {
        v8bf x0 = ldv(&h1N[m][(kc * 32 + q * 8) ^ sw]);
        v8bf x1 = ldv(&h1N[m][((kc + 1) * 32 + q * 8) ^ sw]);
        zA0 = __builtin_amdgcn_mfma_f32_16x16x32_bf16(x0, wp2[kc],     zA0, 0, 0, 0);
        zA1 = __builtin_amdgcn_mfma_f32_16x16x32_bf16(x1, wp2[kc + 1], zA1, 0, 0, 0);
      }
      f32x4 zf = (zA0 + zA1) + (zB0 + zB1);
#pragma unroll
      for (int r = 0; r < 4; ++r) zb[w][q * 4 + r][m] = zf[r];
    }
    __syncthreads();

    // ---- Phase 6: L2 gates + h2_t store (+ last_cell at t==T-1) ----
    {
      float iv = zb[0][row2][col2] + b1i;
      float fv = zb[1][row2][col2] + b1f;
      float gv = zb[2][row2][col2] + b1g;
      float ov = zb[3][row2][col2] + b1o;
      float ig = sigf(iv), fg = sigf(fv), gg = tanhfast(gv), og = sigf(ov);
      c2v = fg * c2v + ig * gg;
      float hn = og * tanhfast(c2v);
      if (t == T_ - 1) {
        last_out[hidx] = hn;            // final outputs; no more consumers of h2
      } else {
        st_llc_u16(&h2g[hidx], (unsigned)__builtin_bit_cast(unsigned short,
                                                            __float2bfloat16(hn)));
      }
    }
    if (t == T_ - 1) break;

    // ---- signal barrier-2 ----
    asm volatile("s_waitcnt vmcnt(0)" ::: "memory");
    __syncthreads();
    if (tid == 0)
      __hip_atomic_fetch_add(cnt, 1u, __ATOMIC_RELAXED, __HIP_MEMORY_SCOPE_AGENT);
  }
}

// ---------------------------------------------------------------------------
extern "C" void kernel_launch(void* const* d_in, const int* in_sizes, int n_in,
                              void* d_out, int out_size, void* d_ws, size_t ws_size,
                              hipStream_t stream) {
  const float* x    = (const float*)d_in[0];
  const float* k0   = (const float*)d_in[1];
  const float* r0   = (const float*)d_in[2];
  const float* b0   = (const float*)d_in[3];
  const float* k1   = (const float*)d_in[4];
  const float* r1   = (const float*)d_in[5];
  const float* b1   = (const float*)d_in[6];
  const float* W    = (const float*)d_in[7];
  const float* bias = (const float*)d_in[8];

  char* ws = (char*)d_ws;
  __hip_bfloat16* Wp1 = (__hip_bfloat16*)(ws + OFF_WP1);
  __hip_bfloat16* Wp2 = (__hip_bfloat16*)(ws + OFF_WP2);
  __hip_bfloat16* WpP = (__hip_bfloat16*)(ws + OFF_WPP);
  __hip_bfloat16* h1g = (__hip_bfloat16*)(ws + OFF_H1G);
  __hip_bfloat16* h2g = (__hip_bfloat16*)(ws + OFF_H2G);
  unsigned*       flg = (unsigned*)(ws + OFF_FLG);

  pack_weights<<<(128 * 18 * 64 + 255) / 256, 256, 0, stream>>>(k0, r0, 64, 2048, 18, 128, Wp1);
  pack_weights<<<(128 * 32 * 64 + 255) / 256, 256, 0, stream>>>(k1, r1, 512, 2048, 32, 128, Wp2);
  pack_weights<<<(4 * 16 * 64 + 255) / 256, 256, 0, stream>>>(W, W, 512, 64, 16, 4, WpP);
  init_state<<<256, 256, 0, stream>>>(h1g, h2g, flg);

  float* outp = (float*)d_out;
  float* last = outp + (size_t)B_ * (T_ - 1) * D_;

  rnn_persist<<<256, 256, 0, stream>>>(x, Wp1, Wp2, WpP, b0, b1, bias,
                                       h1g, h2g, flg, outp, last);
}